// Round 1
// baseline (916.588 us; speedup 1.0000x reference)
//
#include <hip/hip_runtime.h>
#include <hip/hip_bf16.h>

// Problem: out[b, n*128+o] = sum_m x[b, n*128+m] * softmax_m(c[n, m, o])
// B=2048, N_BLOCKS=512, BLOCK_IN=BLOCK_OUT=128, LAYER=65536.
// Memory-bound: ~1.06 GB mandatory traffic vs 13.7us of bf16 MFMA compute.

#define N_BLOCKS 512
#define BI 128
#define BO 128
#define LAYER 65536
#define BATCH 2048

typedef __bf16 bf16x4_t __attribute__((ext_vector_type(4)));
typedef __bf16 bf16x8_t __attribute__((ext_vector_type(8)));
typedef float floatx16_t __attribute__((ext_vector_type(16)));

// ---------------------------------------------------------------------------
// Kernel 1: column softmax over m of c[n][m][o], write TRANSPOSED bf16
// w[n][o][m] so that K (=m) is contiguous for the GEMM's B-fragment reads.
// No LDS: wave-per-column, shuffle reductions; coalesced reads (lanes span o
// via row-resident L1 lines) and fully coalesced 128B writes.
// ---------------------------------------------------------------------------
__global__ __launch_bounds__(256) void softmax_kernel(
    const float* __restrict__ c, __bf16* __restrict__ w) {
  const int n = blockIdx.x;
  const int t = threadIdx.x;
  const int wv = t >> 6;
  const int lane = t & 63;
  const float* cb = c + (size_t)n * (BI * BO);
  __bf16* wb = w + (size_t)n * (BO * BI);

  for (int i = 0; i < 32; ++i) {
    const int o = wv * 32 + i;  // this wave's column
    // lane l holds rows m = l and m = l+64 of column o
    float v0 = cb[lane * BO + o];
    float v1 = cb[(lane + 64) * BO + o];
    float mx = fmaxf(v0, v1);
#pragma unroll
    for (int d = 1; d < 64; d <<= 1) mx = fmaxf(mx, __shfl_xor(mx, d, 64));
    float e0 = __expf(v0 - mx);
    float e1 = __expf(v1 - mx);
    float s = e0 + e1;
#pragma unroll
    for (int d = 1; d < 64; d <<= 1) s += __shfl_xor(s, d, 64);
    float inv = 1.0f / s;
    // transposed store: w[n][o][m], lanes write consecutive bf16 -> coalesced
    wb[o * BI + lane] = (__bf16)(e0 * inv);
    wb[o * BI + lane + 64] = (__bf16)(e1 * inv);
  }
}

// ---------------------------------------------------------------------------
// Kernel 2: per-block GEMM [2048x128] @ [128x128] using mfma_f32_32x32x16_bf16.
// WG = 256 threads (4 waves). Output tile 128(M) x 128(O) per WG.
// Wave wv owns rows [32*wv, 32*wv+32), all 128 output columns (4 MFMA n-tiles).
// LDS: x-tile and w-tile, each [128 rows][16 chunks of 8 bf16] with the chunk
// index XOR-swizzled by (row & 15) -> start banks spread (avoids the 32-way
// conflict of a raw 256B row stride). Total LDS = 64 KB -> 2 WGs/CU.
// ---------------------------------------------------------------------------
__global__ __launch_bounds__(256) void gemm_kernel(
    const float* __restrict__ x, const __bf16* __restrict__ w,
    float* __restrict__ out) {
  __shared__ __bf16 xs[128 * 16 * 8];  // 32 KB, [m][chunk^swz][8]
  __shared__ __bf16 ws_[128 * 16 * 8]; // 32 KB, [o][chunk^swz][8] (chunk = m/8)

  const int n = blockIdx.y;
  const int m_base = blockIdx.x * 128;
  const int t = threadIdx.x;
  const int wv = t >> 6;
  const int lane = t & 63;
  const int lr = lane & 31;
  const int half = lane >> 5;

  // ---- stage x tile: 128x128 fp32 -> bf16 (16 float4 loads per thread) ----
  {
    const float* xg = x + (size_t)m_base * LAYER + n * BI;
#pragma unroll
    for (int i = 0; i < 16; ++i) {
      int lin = t + i * 256;          // float4 index within tile
      int m = lin >> 5;               // row
      int k4 = lin & 31;              // float4 col (k = 4*k4)
      float4 v = *(const float4*)(xg + (size_t)m * LAYER + k4 * 4);
      int chunk = (k4 >> 1) ^ (m & 15);
      bf16x4_t p;
      p[0] = (__bf16)v.x; p[1] = (__bf16)v.y;
      p[2] = (__bf16)v.z; p[3] = (__bf16)v.w;
      *(bf16x4_t*)&xs[(m * 16 + chunk) * 8 + (k4 & 1) * 4] = p;
    }
  }
  // ---- stage w tile: 128x128 bf16 (8 x 16B loads per thread) ----
  {
    const __bf16* wg = w + (size_t)n * (BO * BI);
#pragma unroll
    for (int i = 0; i < 8; ++i) {
      int lin = t + i * 256;          // 16B chunk index within tile
      int o = lin >> 4;
      int mc = lin & 15;              // chunk along m
      bf16x8_t v = *(const bf16x8_t*)(wg + o * BI + mc * 8);
      int chunk = mc ^ (o & 15);
      *(bf16x8_t*)&ws_[(o * 16 + chunk) * 8] = v;
    }
  }
  __syncthreads();

  floatx16_t acc[4];
#pragma unroll
  for (int nt = 0; nt < 4; ++nt)
#pragma unroll
    for (int r = 0; r < 16; ++r) acc[nt][r] = 0.0f;

  const int arow = wv * 32 + lr;  // A fragment row (lane l%32 -> row)
  // K = 128: 8 MFMA steps of k=16. A-frag: A[row=lane&31][k=(lane>>5)*8+j].
#pragma unroll
  for (int step = 0; step < 8; ++step) {
    int kc = step * 2 + half;  // 8-elem chunk index along K
    bf16x8_t a = *(const bf16x8_t*)&xs[(arow * 16 + (kc ^ (arow & 15))) * 8];
#pragma unroll
    for (int nt = 0; nt < 4; ++nt) {
      int ocol = nt * 32 + lr;  // B fragment col
      bf16x8_t b =
          *(const bf16x8_t*)&ws_[(ocol * 16 + (kc ^ (ocol & 15))) * 8];
      acc[nt] = __builtin_amdgcn_mfma_f32_32x32x16_bf16(a, b, acc[nt], 0, 0, 0);
    }
  }

  // ---- epilogue: measured C/D mapping col=lane&31, row=(r&3)+8*(r>>2)+4*half
  float* og = out + (size_t)(m_base + wv * 32) * LAYER + n * BO;
#pragma unroll
  for (int nt = 0; nt < 4; ++nt) {
#pragma unroll
    for (int r = 0; r < 16; ++r) {
      int row = (r & 3) + 8 * (r >> 2) + 4 * half;
      og[(size_t)row * LAYER + nt * 32 + lr] = acc[nt][r];
    }
  }
}

extern "C" void kernel_launch(void* const* d_in, const int* in_sizes, int n_in,
                              void* d_out, int out_size, void* d_ws,
                              size_t ws_size, hipStream_t stream) {
  const float* x = (const float*)d_in[0];   // [2048, 65536]
  const float* c = (const float*)d_in[1];   // [512, 128, 128]
  float* out = (float*)d_out;               // [2048, 65536]
  __bf16* w = (__bf16*)d_ws;                // [512, 128, 128] bf16 transposed: [n][o][m]

  softmax_kernel<<<dim3(N_BLOCKS), dim3(256), 0, stream>>>(c, w);
  gemm_kernel<<<dim3(BATCH / 128, N_BLOCKS), dim3(256), 0, stream>>>(x, w, out);
}